// Round 3
// baseline (120.857 us; speedup 1.0000x reference)
//
#include <hip/hip_runtime.h>
#include <hip/hip_bf16.h>

// QKVAttentionLegacy: qkv (4,3072,1024) fp32, 16 heads, ch=64.
// R3: dbuf K/V (1 barrier/iter), P aliases dead Q region (per-wave private),
// PV operand-swapped (O^T) -> direct coalesced stores, exp2 w/ folded log2e,
// conflict-free LDS swizzles (k/q: xor (row>>3)&7 on 8-elem groups; p: xor
// (quad>>1)<<1 on 8-elem groups). grid 1024 bh-major (XCD locality), 3 blk/CU.

typedef __bf16 bf16_8 __attribute__((ext_vector_type(8)));
typedef __bf16 bf16_4 __attribute__((ext_vector_type(4)));
typedef float floatx4 __attribute__((ext_vector_type(4)));

#define NTHREADS 256
#define STRIDE 72            // bf16 elems per LDS row (144B, 16B-aligned)
#define NSTEPS 16

#if __has_builtin(__builtin_amdgcn_exp2f)
#define EXP2(x) __builtin_amdgcn_exp2f(x)
#else
#define EXP2(x) exp2f(x)
#endif

// (1/8) * log2(e): qk scale + exp->exp2 conversion, folded into Q staging.
// Same rounding count as before: fp32 mul then one bf16 cvt.
#define QSCALE 0.18033688011112042f

// LDS: qp (q tile, later per-wave p tiles) [64][72] @0      9216
//      k dbuf @9216/@18432, v dbuf @27648/@36864            4x9216
#define LDS_BYTES 46080

__global__ __launch_bounds__(NTHREADS, 3)
void attn_kernel(const float* __restrict__ qkv, float* __restrict__ out) {
    __shared__ char smem[LDS_BYTES];
    __bf16* qp_s = (__bf16*)smem;

    const int tid  = threadIdx.x;
    const int wave = tid >> 6;
    const int lane = tid & 63;
    const int quad = lane >> 4;
    const int i16  = lane & 15;

    const int bx = blockIdx.x;           // 1024 = 16 t-tiles * 64 bh (bh fastest)
    const int bh = bx & 63;
    const int t0 = (bx >> 6) * 64;

    const float* qg = qkv + (size_t)bh * 196608;
    const float* kg = qg + 65536;
    const float* vg = qg + 131072;

    // staging coords: f = j*256+tid ; c = f>>4 ; s4 = (f&15)*4
    int sc[4], ss4[4], goff[4], kcol[4];
    #pragma unroll
    for (int j = 0; j < 4; ++j) {
        int f   = j * NTHREADS + tid;
        sc[j]   = f >> 4;
        ss4[j]  = (f & 15) << 2;
        goff[j] = sc[j] * 1024 + ss4[j];
        // transposed-store column for K/Q: group (c>>3) xor row-swizzle (s4>>3)&7
        kcol[j] = (((sc[j] >> 3) ^ ((ss4[j] >> 3) & 7)) << 3) | (sc[j] & 7);
    }

    __bf16* k0 = (__bf16*)(smem + 9216);
    __bf16* k1 = (__bf16*)(smem + 18432);
    __bf16* v0 = (__bf16*)(smem + 27648);
    __bf16* v1 = (__bf16*)(smem + 36864);

    // ---- prologue: stage Q (scaled, transposed, swizzled) + K/V tile 0 ----
    #pragma unroll
    for (int j = 0; j < 4; ++j) {
        float4 q4 = *(const float4*)(qg + goff[j] + t0);
        qp_s[(ss4[j] + 0) * STRIDE + kcol[j]] = (__bf16)(q4.x * QSCALE);
        qp_s[(ss4[j] + 1) * STRIDE + kcol[j]] = (__bf16)(q4.y * QSCALE);
        qp_s[(ss4[j] + 2) * STRIDE + kcol[j]] = (__bf16)(q4.z * QSCALE);
        qp_s[(ss4[j] + 3) * STRIDE + kcol[j]] = (__bf16)(q4.w * QSCALE);
        float4 k4 = *(const float4*)(kg + goff[j]);
        k0[(ss4[j] + 0) * STRIDE + kcol[j]] = (__bf16)k4.x;
        k0[(ss4[j] + 1) * STRIDE + kcol[j]] = (__bf16)k4.y;
        k0[(ss4[j] + 2) * STRIDE + kcol[j]] = (__bf16)k4.z;
        k0[(ss4[j] + 3) * STRIDE + kcol[j]] = (__bf16)k4.w;
        float4 v4 = *(const float4*)(vg + goff[j]);
        bf16_4 pv;
        pv[0] = (__bf16)v4.x; pv[1] = (__bf16)v4.y;
        pv[2] = (__bf16)v4.z; pv[3] = (__bf16)v4.w;
        *(bf16_4*)&v0[sc[j] * STRIDE + ss4[j]] = pv;
    }
    __syncthreads();

    // Q fragments for this wave's 16 t-rows (private slice), in regs all loop
    bf16_8 qf[2];
    {
        int row = wave * 16 + i16;
        int x = (row >> 3) & 7;
        #pragma unroll
        for (int kk = 0; kk < 2; ++kk)
            qf[kk] = *(const bf16_8*)&qp_s[row * STRIDE + (((4 * kk + quad) ^ x) << 3)];
    }

    floatx4 O[4];                        // O^T tiles: rows=c (cn*16+..), cols=t
    #pragma unroll
    for (int cn = 0; cn < 4; ++cn) O[cn] = (floatx4){0.f, 0.f, 0.f, 0.f};
    float l[4] = {0.f, 0.f, 0.f, 0.f};   // per-lane partial row sums (t=4*quad+r)

    const int pxw = (quad >> 1) << 1;    // p-write swizzle
    const int pxr = (i16 >> 3) << 1;     // p-read swizzle
    __bf16* pw = qp_s + (size_t)(wave * 16) * STRIDE;  // wave-private P slice

    for (int is = 0; is < NSTEPS; ++is) {
        // prefetch next K/V tile into regs (hidden under this tile's compute)
        float4 kr[4], vr[4];
        if (is < NSTEPS - 1) {
            const int s0n = (is + 1) * 64;
            #pragma unroll
            for (int j = 0; j < 4; ++j) {
                kr[j] = *(const float4*)(kg + goff[j] + s0n);
                vr[j] = *(const float4*)(vg + goff[j] + s0n);
            }
        }
        const __bf16* kc = (is & 1) ? k1 : k0;
        const __bf16* vc = (is & 1) ? v1 : v0;

        // ---- S' = (Q*log2e/8)^T K ----
        floatx4 S[4];
        #pragma unroll
        for (int n = 0; n < 4; ++n) {
            floatx4 acc = (floatx4){0.f, 0.f, 0.f, 0.f};
            int row = n * 16 + i16;
            int x = (row >> 3) & 7;
            #pragma unroll
            for (int kk = 0; kk < 2; ++kk) {
                bf16_8 kf = *(const bf16_8*)&kc[row * STRIDE + (((4 * kk + quad) ^ x) << 3)];
                acc = __builtin_amdgcn_mfma_f32_16x16x32_bf16(qf[kk], kf, acc, 0, 0, 0);
            }
            S[n] = acc;
        }
        // ---- P = exp2(S') ; accumulate denominators ----
        #pragma unroll
        for (int n = 0; n < 4; ++n)
            #pragma unroll
            for (int r = 0; r < 4; ++r) {
                float p = EXP2(S[n][r]);
                S[n][r] = p;
                l[r] += p;
            }
        // ---- P -> wave-private LDS [t][s] (swizzled, conflict-free) ----
        #pragma unroll
        for (int n = 0; n < 4; ++n) {
            int g = ((2 * n + (i16 >> 3)) ^ pxw) << 3;
            #pragma unroll
            for (int r = 0; r < 4; ++r)
                pw[(4 * quad + r) * STRIDE + g + (i16 & 7)] = (__bf16)S[n][r];
        }
        bf16_8 af[2];
        #pragma unroll
        for (int kk = 0; kk < 2; ++kk)
            af[kk] = *(const bf16_8*)&pw[i16 * STRIDE + (((4 * kk + quad) ^ pxr) << 3)];
        // ---- O^T += V P^T : A=vf (rows=c), B=af (cols=t) ----
        #pragma unroll
        for (int cn = 0; cn < 4; ++cn)
            #pragma unroll
            for (int kk = 0; kk < 2; ++kk) {
                bf16_8 vf = *(const bf16_8*)&vc[(cn * 16 + i16) * STRIDE + kk * 32 + quad * 8];
                O[cn] = __builtin_amdgcn_mfma_f32_16x16x32_bf16(vf, af[kk], O[cn], 0, 0, 0);
            }

        // ---- stage next tile into alternate buffers, single barrier ----
        if (is < NSTEPS - 1) {
            __bf16* kn = (is & 1) ? k0 : k1;
            __bf16* vn = (is & 1) ? v0 : v1;
            #pragma unroll
            for (int j = 0; j < 4; ++j) {
                kn[(ss4[j] + 0) * STRIDE + kcol[j]] = (__bf16)kr[j].x;
                kn[(ss4[j] + 1) * STRIDE + kcol[j]] = (__bf16)kr[j].y;
                kn[(ss4[j] + 2) * STRIDE + kcol[j]] = (__bf16)kr[j].z;
                kn[(ss4[j] + 3) * STRIDE + kcol[j]] = (__bf16)kr[j].w;
                bf16_4 pv;
                pv[0] = (__bf16)vr[j].x; pv[1] = (__bf16)vr[j].y;
                pv[2] = (__bf16)vr[j].z; pv[3] = (__bf16)vr[j].w;
                *(bf16_4*)&vn[sc[j] * STRIDE + ss4[j]] = pv;
            }
            __syncthreads();
        }
    }

    // ---- denominators: reduce over 16-lane groups, redistribute t-wise ----
    float linv;
    {
        float inv[4];
        #pragma unroll
        for (int r = 0; r < 4; ++r) {
            float s = l[r];
            #pragma unroll
            for (int off = 1; off < 16; off <<= 1)
                s += __shfl_xor(s, off);
            inv[r] = 1.0f / s;
        }
        float* lf = (float*)(smem + wave * 16 * 144);  // own dead P slice
        if (i16 == 0) {
            #pragma unroll
            for (int r = 0; r < 4; ++r) lf[4 * quad + r] = inv[r];
        }
        linv = lf[i16];                  // in-wave ds ordering; t = i16
    }

    // ---- direct store: lane holds (c = cn*16+4*quad+r, t = T0+i16) ----
    float* og = out + (size_t)bh * 65536 + t0 + wave * 16;
    #pragma unroll
    for (int cn = 0; cn < 4; ++cn)
        #pragma unroll
        for (int r = 0; r < 4; ++r)
            og[(cn * 16 + 4 * quad + r) * 1024 + i16] = O[cn][r] * linv;
}

extern "C" void kernel_launch(void* const* d_in, const int* in_sizes, int n_in,
                              void* d_out, int out_size, void* d_ws, size_t ws_size,
                              hipStream_t stream) {
    const float* qkv = (const float*)d_in[0];
    float* out = (float*)d_out;
    attn_kernel<<<dim3(1024), dim3(NTHREADS), 0, stream>>>(qkv, out);
}

// Round 5
// 109.664 us; speedup vs baseline: 1.1021x; 1.1021x over previous
//
#include <hip/hip_runtime.h>
#include <hip/hip_bf16.h>

// QKVAttentionLegacy: qkv (4,3072,1024) fp32, 16 heads, ch=64.
// R5: LDS-throughput attack. Each wave owns 32 t (2 MFMA n-tiles) so every
// kf/vf ds_read_b128 feeds 2 MFMAs (halves dominant LDS cost). S^T orientation
// (mfma(kf,qf)): C regs = 4 contiguous s -> P via packed ds_write_b64 into the
// wave's dead-Q rows (2-way banks = free, intra-wave ordering, no barrier);
// per-lane denominator (2 end shuffles); O^T direct coalesced stores.
// BM=128, grid 512 (bh-fastest for XCD L2 locality), single-buffer + reg prefetch.

typedef __bf16 bf16_8 __attribute__((ext_vector_type(8)));
typedef __bf16 bf16_4 __attribute__((ext_vector_type(4)));
typedef float floatx4 __attribute__((ext_vector_type(4)));

#define NTHREADS 256
#define STRIDE 72            // bf16 elems per LDS row (144 B)
#define NSTEPS 16

#if __has_builtin(__builtin_amdgcn_exp2f)
#define EXP2(x) __builtin_amdgcn_exp2f(x)
#else
#define EXP2(x) exp2f(x)
#endif
// (1/8)*log2(e): qk scale + exp->exp2, folded into Q staging (one bf16 rounding).
#define QSCALE 0.18033688011112042f

// LDS: q_s [128][72]bf16 @0 (18432; rows [32w,32w+32) become wave w's P scratch)
//      k_s [64][72] @18432 (K^T [s][c]) | v_s [64][72] @27648 (V [c][s])
#define LDS_BYTES 36864

__global__ __launch_bounds__(NTHREADS, 2)
void attn_kernel(const float* __restrict__ qkv, float* __restrict__ out) {
    __shared__ char smem[LDS_BYTES];
    __bf16* q_s = (__bf16*)smem;
    __bf16* k_s = (__bf16*)(smem + 18432);
    __bf16* v_s = (__bf16*)(smem + 27648);

    const int tid  = threadIdx.x;
    const int wave = tid >> 6;
    const int lane = tid & 63;
    const int quad = lane >> 4;
    const int i16  = lane & 15;

    const int bx = blockIdx.x;           // 512 = 8 t-tiles * 64 bh (bh fastest)
    const int bh = bx & 63;
    const int t0 = (bx >> 6) << 7;       // *128

    const float* qg = qkv + (size_t)bh * 196608;
    const float* kg = qg + 65536;
    const float* vg = qg + 131072;

    // K/V staging coords (R2-verified swizzle): f=j*256+tid; c=f>>4; s4=(f&15)*4
    int sc[4], ss4[4], goff[4], swz[4];
    #pragma unroll
    for (int j = 0; j < 4; ++j) {
        int f   = j * NTHREADS + tid;
        sc[j]   = f >> 4;
        ss4[j]  = (f & 15) << 2;
        goff[j] = sc[j] * 1024 + ss4[j];
        swz[j]  = sc[j] ^ ((f & 7) << 3);   // x=(row>>2)&7 = f&7 for rows s4..s4+3
    }

    // ---- prologue: Q (128 t x 64 c, scaled+transposed+swizzled) ----
    #pragma unroll
    for (int j = 0; j < 8; ++j) {
        int f  = j * NTHREADS + tid;
        int c  = f >> 5;                  // 0..63
        int t4 = (f & 31) << 2;           // 0..124 ; x=(t4>>2)&7 = f&7
        int sq = c ^ ((f & 7) << 3);
        float4 q4 = *(const float4*)(qg + c * 1024 + t0 + t4);
        q_s[(t4 + 0) * STRIDE + sq] = (__bf16)(q4.x * QSCALE);
        q_s[(t4 + 1) * STRIDE + sq] = (__bf16)(q4.y * QSCALE);
        q_s[(t4 + 2) * STRIDE + sq] = (__bf16)(q4.z * QSCALE);
        q_s[(t4 + 3) * STRIDE + sq] = (__bf16)(q4.w * QSCALE);
    }
    // ---- K/V tile 0 ----
    #pragma unroll
    for (int j = 0; j < 4; ++j) {
        float4 k4 = *(const float4*)(kg + goff[j]);
        k_s[(ss4[j] + 0) * STRIDE + swz[j]] = (__bf16)k4.x;
        k_s[(ss4[j] + 1) * STRIDE + swz[j]] = (__bf16)k4.y;
        k_s[(ss4[j] + 2) * STRIDE + swz[j]] = (__bf16)k4.z;
        k_s[(ss4[j] + 3) * STRIDE + swz[j]] = (__bf16)k4.w;
        float4 v4 = *(const float4*)(vg + goff[j]);
        bf16_4 pv;
        pv[0] = (__bf16)v4.x; pv[1] = (__bf16)v4.y;
        pv[2] = (__bf16)v4.z; pv[3] = (__bf16)v4.w;
        *(bf16_4*)&v_s[sc[j] * STRIDE + ss4[j]] = pv;
    }
    __syncthreads();

    // Q B-frags for this wave's two 16-t tiles (B[k=c][n=t]), regs all loop
    bf16_8 qf[2][2];
    #pragma unroll
    for (int tt = 0; tt < 2; ++tt) {
        int row = wave * 32 + tt * 16 + i16;
        int x = (row >> 2) & 7;
        #pragma unroll
        for (int kk = 0; kk < 2; ++kk)
            qf[tt][kk] = *(const bf16_8*)&q_s[row * STRIDE + ((((kk << 2) | quad) ^ x) << 3)];
    }

    floatx4 O[2][4];                     // [tt][cn] O^T: row c=cn*16+4q+r, col t
    #pragma unroll
    for (int tt = 0; tt < 2; ++tt)
        #pragma unroll
        for (int cn = 0; cn < 4; ++cn) O[tt][cn] = (floatx4){0.f, 0.f, 0.f, 0.f};
    float l[2] = {0.f, 0.f};             // per-lane denominator partials

    __bf16* pw = q_s + (size_t)(wave * 32) * STRIDE;  // wave-private P [32t][64s]

    for (int is = 0; is < NSTEPS; ++is) {
        float4 kr[4], vr[4];
        if (is < NSTEPS - 1) {
            const int s0n = (is + 1) * 64;
            #pragma unroll
            for (int j = 0; j < 4; ++j) {
                kr[j] = *(const float4*)(kg + goff[j] + s0n);
                vr[j] = *(const float4*)(vg + goff[j] + s0n);
            }
        }

        // ---- S^T = K (Qs)^T : each kf read feeds both t-tiles ----
        floatx4 St[2][4];
        #pragma unroll
        for (int sb = 0; sb < 4; ++sb) {
            floatx4 a0 = (floatx4){0.f, 0.f, 0.f, 0.f};
            floatx4 a1 = (floatx4){0.f, 0.f, 0.f, 0.f};
            int row = sb * 16 + i16;
            int x = (row >> 2) & 7;
            #pragma unroll
            for (int kk = 0; kk < 2; ++kk) {
                bf16_8 kf = *(const bf16_8*)&k_s[row * STRIDE + ((((kk << 2) | quad) ^ x) << 3)];
                a0 = __builtin_amdgcn_mfma_f32_16x16x32_bf16(kf, qf[0][kk], a0, 0, 0, 0);
                a1 = __builtin_amdgcn_mfma_f32_16x16x32_bf16(kf, qf[1][kk], a1, 0, 0, 0);
            }
            St[0][sb] = a0;
            St[1][sb] = a1;
        }
        // ---- P = exp2(S^T); pack 4 contiguous s -> one ds_write_b64 ----
        // lane (q,i16) reg r of St[tt][sb] = P^T[s=sb*16+4q+r][t=tt*16+i16]
        #pragma unroll
        for (int tt = 0; tt < 2; ++tt)
            #pragma unroll
            for (int sb = 0; sb < 4; ++sb) {
                float p0 = EXP2(St[tt][sb][0]);
                float p1 = EXP2(St[tt][sb][1]);
                float p2 = EXP2(St[tt][sb][2]);
                float p3 = EXP2(St[tt][sb][3]);
                l[tt] += (p0 + p1) + (p2 + p3);
                bf16_4 pk;
                pk[0] = (__bf16)p0; pk[1] = (__bf16)p1;
                pk[2] = (__bf16)p2; pk[3] = (__bf16)p3;
                *(bf16_4*)&pw[(tt * 16 + i16) * STRIDE + sb * 16 + quad * 4] = pk;
            }
        // ---- af B-frags (intra-wave DS ordering; private region, no barrier) ----
        bf16_8 af[2][2];
        #pragma unroll
        for (int tt = 0; tt < 2; ++tt)
            #pragma unroll
            for (int kk = 0; kk < 2; ++kk)
                af[tt][kk] = *(const bf16_8*)&pw[(tt * 16 + i16) * STRIDE + kk * 32 + quad * 8];
        // ---- O^T += V P^T : each vf read feeds both t-tiles ----
        #pragma unroll
        for (int cn = 0; cn < 4; ++cn)
            #pragma unroll
            for (int kk = 0; kk < 2; ++kk) {
                bf16_8 vf = *(const bf16_8*)&v_s[(cn * 16 + i16) * STRIDE + kk * 32 + quad * 8];
                O[0][cn] = __builtin_amdgcn_mfma_f32_16x16x32_bf16(vf, af[0][kk], O[0][cn], 0, 0, 0);
                O[1][cn] = __builtin_amdgcn_mfma_f32_16x16x32_bf16(vf, af[1][kk], O[1][cn], 0, 0, 0);
            }

        if (is < NSTEPS - 1) {
            __syncthreads();             // all waves done reading k_s/v_s
            #pragma unroll
            for (int j = 0; j < 4; ++j) {
                k_s[(ss4[j] + 0) * STRIDE + swz[j]] = (__bf16)kr[j].x;
                k_s[(ss4[j] + 1) * STRIDE + swz[j]] = (__bf16)kr[j].y;
                k_s[(ss4[j] + 2) * STRIDE + swz[j]] = (__bf16)kr[j].z;
                k_s[(ss4[j] + 3) * STRIDE + swz[j]] = (__bf16)kr[j].w;
                bf16_4 pv;
                pv[0] = (__bf16)vr[j].x; pv[1] = (__bf16)vr[j].y;
                pv[2] = (__bf16)vr[j].z; pv[3] = (__bf16)vr[j].w;
                *(bf16_4*)&v_s[sc[j] * STRIDE + ss4[j]] = pv;
            }
            __syncthreads();             // new tile visible
        }
    }

    // ---- denominators: sum the 4 quads (same i16/t column), per-lane ----
    float* og = out + (size_t)bh * 65536 + t0 + wave * 32;
    #pragma unroll
    for (int tt = 0; tt < 2; ++tt) {
        float s = l[tt];
        s += __shfl_xor(s, 16);
        s += __shfl_xor(s, 32);
        const float linv = 1.0f / s;
        #pragma unroll
        for (int cn = 0; cn < 4; ++cn)
            #pragma unroll
            for (int r = 0; r < 4; ++r)
                og[(cn * 16 + 4 * quad + r) * 1024 + tt * 16 + i16] = O[tt][cn][r] * linv;
    }
}

extern "C" void kernel_launch(void* const* d_in, const int* in_sizes, int n_in,
                              void* d_out, int out_size, void* d_ws, size_t ws_size,
                              hipStream_t stream) {
    const float* qkv = (const float*)d_in[0];
    float* out = (float*)d_out;
    attn_kernel<<<dim3(512), dim3(NTHREADS), 0, stream>>>(qkv, out);
}